// Round 9
// baseline (201.082 us; speedup 1.0000x reference)
//
#include <hip/hip_runtime.h>
#include <hip/hip_bf16.h>
#include <stdint.h>

// ---------------------------------------------------------------------------
// SelfAttention fused pipeline. FP32 device buffers; bf16 MFMA, fp32 accum.
//   K0: convert x, qkv_w, proj_w fp32 -> bf16 workspace
//   K1: qkv = x @ qkv_w^T (+RoPE; q pre-scaled by 0.125*log2e) ->
//       q,k [B,H,N,64]; V TRANSPOSED [B,H,64,N]
//   K2: flash attention, KV-split-4; SHUFFLE-FREE PV via K=16 MFMA
//       (P C-layout == PV B-fragment layout for 16x16x16)
//   K3: out = aws @ proj_w^T + proj_b (fp32)      -> d_out fp32
// B=2 N=2048 D=768 H=12 Dh=64.
// ---------------------------------------------------------------------------

typedef unsigned short u16;
typedef __attribute__((ext_vector_type(8))) short s16x8;   // 8 x bf16 (4 VGPRs)
typedef __attribute__((ext_vector_type(4))) short s16x4;   // 4 x bf16 (2 VGPRs)
typedef __attribute__((ext_vector_type(4))) float f32x4;   // MFMA accumulator

#define MFMA16(a, b, c) __builtin_amdgcn_mfma_f32_16x16x32_bf16((a), (b), (c), 0, 0, 0)

// K=16 MFMA via inline asm (mnemonic per gfx950 ISA §10; register-only asm
// keeps compiler-managed waitcnt on the load-producing inputs).
__device__ __forceinline__ f32x4 mfma_k16(s16x4 a, s16x4 b, f32x4 c) {
    asm("v_mfma_f32_16x16x16_bf16 %0, %1, %2, %0" : "+v"(c) : "v"(a), "v"(b));
    return c;
}

__device__ __forceinline__ u16 f2bf(float f) {  // round-to-nearest-even
    uint32_t u = __float_as_uint(f);
    u = u + 0x7fffu + ((u >> 16) & 1u);
    return (u16)(u >> 16);
}
__device__ __forceinline__ uint32_t pk2(float lo, float hi) {
    return (uint32_t)f2bf(lo) | ((uint32_t)f2bf(hi) << 16);
}

// ---------------------------------------------------------------------------
// K0: fp32 -> bf16 elementwise convert (n divisible by 4).
// ---------------------------------------------------------------------------
__global__ __launch_bounds__(256)
void k_cvt(const float* __restrict__ src, u16* __restrict__ dst, int n4)
{
    const int i = blockIdx.x * 256 + threadIdx.x;
    if (i < n4) {
        const float4 v = ((const float4*)src)[i];
        ushort4 o;
        o.x = f2bf(v.x); o.y = f2bf(v.y); o.z = f2bf(v.z); o.w = f2bf(v.w);
        ((ushort4*)dst)[i] = o;
    }
}

// ---------------------------------------------------------------------------
// K1: QKV GEMM (128x128 tile, BK=32) with fused RoPE epilogue.
// grid (32, 18), 256 threads. V written TRANSPOSED vtws[b,h,dh,tok];
// Q pre-scaled by 0.125*log2(e) so k_attn's softmax runs in exp2 domain.
// ---------------------------------------------------------------------------
__global__ __launch_bounds__(256, 2)
void k_qkv_rope(const u16* __restrict__ X,     // [4096][768] bf16
                const u16* __restrict__ W,     // [2304][768] bf16
                const float* __restrict__ SIN, // [2048][64] fp32
                const float* __restrict__ COS, // [2048][64] fp32
                u16* __restrict__ qws, u16* __restrict__ kws, u16* __restrict__ vtws)
{
    __shared__ u16 As[128 * 32];
    __shared__ u16 Bs[128 * 32];
    const int t  = threadIdx.x;
    const int l  = t & 63;
    const int w  = t >> 6;
    const int cl = l & 15, gh = l >> 4;
    const int brow = blockIdx.x * 128;
    const int bcol = blockIdx.y * 128;
    const int wr = (w >> 1) * 64;
    const int wc = (w & 1) * 64;

    const int srow = w * 16 + (l >> 2);
    const int scol = (l & 3) * 8;
    const u16* gA = X + (size_t)(brow + srow) * 768 + scol;
    const u16* gB = W + (size_t)(bcol + srow) * 768 + scol;

    f32x4 acc[4][4] = {};

    for (int kt = 0; kt < 24; ++kt) {
        const int k0 = kt * 32;
        const s16x8 a0 = *(const s16x8*)(gA + k0);
        const s16x8 a1 = *(const s16x8*)(gA + k0 + 64 * 768);
        const s16x8 b0 = *(const s16x8*)(gB + k0);
        const s16x8 b1 = *(const s16x8*)(gB + k0 + 64 * 768);
        __syncthreads();
        *(s16x8*)(As + srow * 32 + scol)        = a0;
        *(s16x8*)(As + (srow + 64) * 32 + scol) = a1;
        *(s16x8*)(Bs + srow * 32 + scol)        = b0;
        *(s16x8*)(Bs + (srow + 64) * 32 + scol) = b1;
        __syncthreads();

        s16x8 af[4], bv[4];
        #pragma unroll
        for (int m = 0; m < 4; ++m)
            af[m] = *(const s16x8*)(As + (wr + m * 16 + cl) * 32 + gh * 8);
        #pragma unroll
        for (int n = 0; n < 4; ++n)
            bv[n] = *(const s16x8*)(Bs + (wc + n * 16 + cl) * 32 + gh * 8);
        #pragma unroll
        for (int m = 0; m < 4; ++m)
            #pragma unroll
            for (int n = 0; n < 4; ++n)
                acc[m][n] = MFMA16(af[m], bv[n], acc[m][n]);
    }

    const int seg   = (bcol + wc) >> 6;   // 0..35
    const int which = seg / 12;           // 0:q 1:k 2:v
    const int h     = seg % 12;
    // q pre-scale: 0.125 * log2(e) -> scores land in exp2 domain
    const float qscl = (which == 0) ? 0.1803368801111244f : 1.0f;

    #pragma unroll
    for (int m = 0; m < 4; ++m) {
        #pragma unroll
        for (int jj = 0; jj < 4; ++jj) {
            const int row = brow + wr + m * 16 + gh * 4 + jj;  // 0..4095
            const int b   = row >> 11;
            const int tok = row & 2047;
            if (which == 2) {
                u16* vtb = vtws + (size_t)(b * 12 + h) * 64 * 2048;
                #pragma unroll
                for (int n = 0; n < 4; ++n)
                    vtb[(size_t)(n * 16 + cl) * 2048 + tok] = f2bf(acc[m][n][jj]);
            } else {
                u16* outp = (which == 0) ? qws : kws;
                u16* orow = outp + ((size_t)(b * 12 + h) * 2048 + tok) * 64;
                const float* srow2 = SIN + tok * 64;
                const float* crow2 = COS + tok * 64;
                #pragma unroll
                for (int n = 0; n < 4; ++n) {
                    const int dh = n * 16 + cl;
                    const float v = acc[m][n][jj];
                    const float partner = (n < 2) ? -acc[m][n + 2][jj] : acc[m][n - 2][jj];
                    orow[dh] = f2bf((v * crow2[dh] + partner * srow2[dh]) * qscl);
                }
            }
        }
    }
}

// ---------------------------------------------------------------------------
// K2: flash attention, KV-split-4. grid 1536 x 256 threads.
// Block = 32 q-rows; 4 waves each process a disjoint 8-tile KV quarter.
// Swapped QK^T (16x16x32) -> lane-local exp2 softmax with defer-max ->
// P packed in-register is DIRECTLY the B-fragment of the 16x16x16 PV MFMA
// (k = gh*4+jj matches C-layout rows) -> zero cross-lane shuffles.
// V^T A-fragments: 16 x 8B contiguous loads, issued at tile top.
// End: LDS combine of per-wave (m, l, O) partials; wave w merges n=w slice.
// ---------------------------------------------------------------------------
__global__ __launch_bounds__(256)
void k_attn(const u16* __restrict__ Qg, const u16* __restrict__ Kg,
            const u16* __restrict__ VTg, u16* __restrict__ Og)
{
    __shared__ f32x4 OL[4][64][8];    // [wave][lane][m*4+n] partial O^T, 32 KB
    __shared__ float2 ML[4][64][2];   // [wave][lane][m] = (m_run, l_run), 4 KB

    const int t  = threadIdx.x;
    const int l  = t & 63;
    const int w  = t >> 6;                      // 0..3 = KV quarter
    const int cl = l & 15, gh = l >> 4;

    // bijective swizzle: XCD (= i%8, assumed) owns 3 consecutive heads
    const int i  = blockIdx.x;                  // 0..1535
    const int bh = (i & 7) * 3 + ((i >> 3) % 3);
    const int qt = i / 24;                      // 0..63
    const int qb = qt * 32;                     // block's 32 q rows

    const u16* Q  = Qg  + (size_t)bh * 2048 * 64;
    const u16* K  = Kg  + (size_t)bh * 2048 * 64;
    const u16* VT = VTg + (size_t)bh * 64 * 2048;

    // Q B-fragments (same for all 4 waves): col q = qb+m*16+cl
    s16x8 qf[2][2];
    #pragma unroll
    for (int m = 0; m < 2; ++m)
        #pragma unroll
        for (int ks = 0; ks < 2; ++ks)
            qf[m][ks] = *(const s16x8*)(Q + (((qb + m * 16 + cl) << 6) + ks * 32 + gh * 8));

    f32x4 o[2][4] = {};            // O^T: lane col q=cl, row dh=n*16+gh*4+jj
    float mrun[2] = { -3e38f, -3e38f };
    float lrun[2] = { 0.f, 0.f };

    // per-lane int32 element-offset bases (advance by constants per tile)
    const int kbase0 = ((w * 8 * 64 + cl) << 6) + gh * 8;   // K: +nk*1024, +ks*32
    const int vbase0 = (cl << 11) + w * 8 * 64 + gh * 4;    // VT: +n*32768, +nk*16

    for (int kt = 0; kt < 8; ++kt) {
        const int kb = kbase0 + kt * 4096;     // 64 rows * 64 elem per tile
        const int vb = vbase0 + kt * 64;       // 64 cols per tile

        // ---- issue V^T A-fragments early (4 bf16 each, k = gh*4+j) ----
        s16x4 vf[4][4];                        // [n][nk]
        #pragma unroll
        for (int n = 0; n < 4; ++n)
            #pragma unroll
            for (int nk = 0; nk < 4; ++nk)
                vf[n][nk] = *(const s16x4*)(VT + (vb + n * 32768 + nk * 16));

        // ---- S^T = K x Q (scores already in exp2 domain) ----
        f32x4 st[2][4] = {};
        #pragma unroll
        for (int nk = 0; nk < 4; ++nk) {
            #pragma unroll
            for (int ks = 0; ks < 2; ++ks) {
                const s16x8 kf = *(const s16x8*)(K + (kb + nk * 1024 + ks * 32));
                st[0][nk] = MFMA16(kf, qf[0][ks], st[0][nk]);
                st[1][nk] = MFMA16(kf, qf[1][ks], st[1][nk]);
            }
        }

        // ---- lane-local online softmax, defer-max (THR=8, log2 domain);
        //      packed P pairs form the PV B-fragments directly ----
        union { uint32_t u[2]; s16x4 v; } pb[2][4];
        #pragma unroll
        for (int m = 0; m < 2; ++m) {
            float pm = st[m][0][0];
            #pragma unroll
            for (int nk = 0; nk < 4; ++nk)
                #pragma unroll
                for (int jj = 0; jj < 4; ++jj)
                    pm = fmaxf(pm, st[m][nk][jj]);
            pm = fmaxf(pm, __shfl_xor(pm, 16));
            pm = fmaxf(pm, __shfl_xor(pm, 32));
            if (!__all(pm - mrun[m] <= 8.f)) {
                const float mnew = fmaxf(mrun[m], pm);
                const float al = exp2f(mrun[m] - mnew);
                #pragma unroll
                for (int n = 0; n < 4; ++n)
                    #pragma unroll
                    for (int jj = 0; jj < 4; ++jj)
                        o[m][n][jj] *= al;
                lrun[m] *= al;
                mrun[m] = mnew;
            }
            float sum = 0.f;
            #pragma unroll
            for (int nk = 0; nk < 4; ++nk) {
                const float p0 = exp2f(st[m][nk][0] - mrun[m]);
                const float p1 = exp2f(st[m][nk][1] - mrun[m]);
                const float p2 = exp2f(st[m][nk][2] - mrun[m]);
                const float p3 = exp2f(st[m][nk][3] - mrun[m]);
                sum += (p0 + p1) + (p2 + p3);
                pb[m][nk].u[0] = pk2(p0, p1);
                pb[m][nk].u[1] = pk2(p2, p3);
            }
            lrun[m] += sum;   // per-replica partial; reduced before combine
        }

        // ---- PV: O^T += V^T x P^T per 16-k window, zero shuffles ----
        #pragma unroll
        for (int nk = 0; nk < 4; ++nk)
            #pragma unroll
            for (int n = 0; n < 4; ++n) {
                o[0][n] = mfma_k16(vf[n][nk], pb[0][nk].v, o[0][n]);
                o[1][n] = mfma_k16(vf[n][nk], pb[1][nk].v, o[1][n]);
            }
    }

    // ---- publish partials: reduce lrun across gh replicas, write LDS ----
    #pragma unroll
    for (int m = 0; m < 2; ++m) {
        float lr = lrun[m];
        lr += __shfl_xor(lr, 16);
        lr += __shfl_xor(lr, 32);
        ML[w][l][m] = make_float2(mrun[m], lr);
        #pragma unroll
        for (int n = 0; n < 4; ++n)
            OL[w][l][m * 4 + n] = o[m][n];
    }
    __syncthreads();

    // ---- combine: wave w merges the n=w slice of all 4 partials ----
    const int b = bh / 12, h = bh % 12;
    #pragma unroll
    for (int m = 0; m < 2; ++m) {
        float2 s[4];
        float mmax = -3e38f;
        #pragma unroll
        for (int w2 = 0; w2 < 4; ++w2) {
            s[w2] = ML[w2][l][m];
            mmax = fmaxf(mmax, s[w2].x);
        }
        f32x4 oacc = {};
        float lacc = 0.f;
        #pragma unroll
        for (int w2 = 0; w2 < 4; ++w2) {
            const float sc = exp2f(s[w2].x - mmax);
            oacc += OL[w2][l][m * 4 + w] * sc;
            lacc += s[w2].y * sc;
        }
        const float inv = 1.0f / lacc;
        const int tok = qb + m * 16 + cl;
        u16* orow = Og + ((size_t)(b * 2048 + tok)) * 768 + h * 64 + w * 16 + gh * 4;
        uint2 pkv;
        pkv.x = pk2(oacc[0] * inv, oacc[1] * inv);
        pkv.y = pk2(oacc[2] * inv, oacc[3] * inv);
        *(uint2*)orow = pkv;
    }
}

// ---------------------------------------------------------------------------
// K3: output projection + bias (fp32 out). grid (32, 6).
// ---------------------------------------------------------------------------
__global__ __launch_bounds__(256, 2)
void k_proj(const u16* __restrict__ A,      // [4096][768] bf16
            const u16* __restrict__ W,      // [768][768] bf16
            const float* __restrict__ BIAS, // [768] fp32
            float* __restrict__ OUT)        // [4096][768] fp32
{
    __shared__ u16 As[128 * 32];
    __shared__ u16 Bs[128 * 32];
    const int t  = threadIdx.x;
    const int l  = t & 63;
    const int w  = t >> 6;
    const int cl = l & 15, gh = l >> 4;
    const int brow = blockIdx.x * 128;
    const int bcol = blockIdx.y * 128;
    const int wr = (w >> 1) * 64;
    const int wc = (w & 1) * 64;

    const int srow = w * 16 + (l >> 2);
    const int scol = (l & 3) * 8;
    const u16* gA = A + (size_t)(brow + srow) * 768 + scol;
    const u16* gB = W + (size_t)(bcol + srow) * 768 + scol;

    f32x4 acc[4][4] = {};

    for (int kt = 0; kt < 24; ++kt) {
        const int k0 = kt * 32;
        const s16x8 a0 = *(const s16x8*)(gA + k0);
        const s16x8 a1 = *(const s16x8*)(gA + k0 + 64 * 768);
        const s16x8 b0 = *(const s16x8*)(gB + k0);
        const s16x8 b1 = *(const s16x8*)(gB + k0 + 64 * 768);
        __syncthreads();
        *(s16x8*)(As + srow * 32 + scol)        = a0;
        *(s16x8*)(As + (srow + 64) * 32 + scol) = a1;
        *(s16x8*)(Bs + srow * 32 + scol)        = b0;
        *(s16x8*)(Bs + (srow + 64) * 32 + scol) = b1;
        __syncthreads();

        s16x8 af[4], bv[4];
        #pragma unroll
        for (int m = 0; m < 4; ++m)
            af[m] = *(const s16x8*)(As + (wr + m * 16 + cl) * 32 + gh * 8);
        #pragma unroll
        for (int n = 0; n < 4; ++n)
            bv[n] = *(const s16x8*)(Bs + (wc + n * 16 + cl) * 32 + gh * 8);
        #pragma unroll
        for (int m = 0; m < 4; ++m)
            #pragma unroll
            for (int n = 0; n < 4; ++n)
                acc[m][n] = MFMA16(af[m], bv[n], acc[m][n]);
    }

    #pragma unroll
    for (int m = 0; m < 4; ++m) {
        #pragma unroll
        for (int jj = 0; jj < 4; ++jj) {
            const int row = brow + wr + m * 16 + gh * 4 + jj;
            #pragma unroll
            for (int n = 0; n < 4; ++n) {
                const int col = bcol + wc + n * 16 + cl;
                OUT[(size_t)row * 768 + col] = acc[m][n][jj] + BIAS[col];
            }
        }
    }
}

// ---------------------------------------------------------------------------
extern "C" void kernel_launch(void* const* d_in, const int* in_sizes, int n_in,
                              void* d_out, int out_size, void* d_ws, size_t ws_size,
                              hipStream_t stream)
{
    const float* x     = (const float*)d_in[0];
    const float* sinp  = (const float*)d_in[1];
    const float* cosp  = (const float*)d_in[2];
    const float* qkv_w = (const float*)d_in[3];
    const float* projw = (const float*)d_in[4];
    const float* projb = (const float*)d_in[5];
    float* out = (float*)d_out;

    const size_t N_X  = (size_t)4096 * 768;
    const size_t N_WQ = (size_t)2304 * 768;
    const size_t N_WP = (size_t)768 * 768;
    const size_t SEG  = (size_t)2 * 12 * 2048 * 64;

    u16* xbf   = (u16*)d_ws;
    u16* wqkv  = xbf + N_X;
    u16* wproj = wqkv + N_WQ;
    u16* qws   = wproj + N_WP;
    u16* kws   = qws + SEG;
    u16* vtws  = kws + SEG;   // transposed V [B,H,64,2048]
    u16* aws   = vtws + SEG;

    k_cvt<<<(int)(N_X  / 4 + 255) / 256, 256, 0, stream>>>(x,     xbf,   (int)(N_X  / 4));
    k_cvt<<<(int)(N_WQ / 4 + 255) / 256, 256, 0, stream>>>(qkv_w, wqkv,  (int)(N_WQ / 4));
    k_cvt<<<(int)(N_WP / 4 + 255) / 256, 256, 0, stream>>>(projw, wproj, (int)(N_WP / 4));

    k_qkv_rope<<<dim3(32, 18), 256, 0, stream>>>(xbf, wqkv, sinp, cosp, qws, kws, vtws);
    k_attn    <<<1536, 256, 0, stream>>>(qws, kws, vtws, aws);
    k_proj    <<<dim3(32, 6),  256, 0, stream>>>(aws, wproj, projb, out);
}

// Round 10
// 158.845 us; speedup vs baseline: 1.2659x; 1.2659x over previous
//
#include <hip/hip_runtime.h>
#include <hip/hip_bf16.h>
#include <stdint.h>

// ---------------------------------------------------------------------------
// SelfAttention fused pipeline. FP32 device buffers; bf16 MFMA, fp32 accum.
//   K0: convert x, qkv_w, proj_w fp32 -> bf16 workspace
//   K1: qkv = x @ qkv_w^T (+RoPE; q pre-scaled by 0.125*log2e) ->
//       q,k [B,H,N,64]; V TRANSPOSED [B,H,64,N]
//   K2: flash attention, KV-split-4 (round-8 structure) + K reg double-buffer
//       prefetch + native v_exp_f32 + s_setprio around MFMA clusters
//   K3: out = aws @ proj_w^T + proj_b (fp32)      -> d_out fp32
// B=2 N=2048 D=768 H=12 Dh=64.
// ---------------------------------------------------------------------------

typedef unsigned short u16;
typedef __attribute__((ext_vector_type(8))) short s16x8;   // 8 x bf16 (4 VGPRs)
typedef __attribute__((ext_vector_type(4))) float f32x4;   // MFMA accumulator

#define MFMA16(a, b, c) __builtin_amdgcn_mfma_f32_16x16x32_bf16((a), (b), (c), 0, 0, 0)

__device__ __forceinline__ u16 f2bf(float f) {  // round-to-nearest-even
    uint32_t u = __float_as_uint(f);
    u = u + 0x7fffu + ((u >> 16) & 1u);
    return (u16)(u >> 16);
}
__device__ __forceinline__ uint32_t pk2(float lo, float hi) {
    return (uint32_t)f2bf(lo) | ((uint32_t)f2bf(hi) << 16);
}
// raw v_exp_f32 (= 2^x exactly); args here are in [-inf, 8] so no range issues
__device__ __forceinline__ float fexp2(float x) { return __builtin_amdgcn_exp2f(x); }

// ---------------------------------------------------------------------------
// K0: fp32 -> bf16 elementwise convert (n divisible by 4).
// ---------------------------------------------------------------------------
__global__ __launch_bounds__(256)
void k_cvt(const float* __restrict__ src, u16* __restrict__ dst, int n4)
{
    const int i = blockIdx.x * 256 + threadIdx.x;
    if (i < n4) {
        const float4 v = ((const float4*)src)[i];
        ushort4 o;
        o.x = f2bf(v.x); o.y = f2bf(v.y); o.z = f2bf(v.z); o.w = f2bf(v.w);
        ((ushort4*)dst)[i] = o;
    }
}

// ---------------------------------------------------------------------------
// K1: QKV GEMM (128x128 tile, BK=32) with fused RoPE epilogue.
// grid (32, 18), 256 threads. V written TRANSPOSED vtws[b,h,dh,tok];
// Q pre-scaled by 0.125*log2(e) so k_attn's softmax runs in exp2 domain.
// ---------------------------------------------------------------------------
__global__ __launch_bounds__(256, 2)
void k_qkv_rope(const u16* __restrict__ X,     // [4096][768] bf16
                const u16* __restrict__ W,     // [2304][768] bf16
                const float* __restrict__ SIN, // [2048][64] fp32
                const float* __restrict__ COS, // [2048][64] fp32
                u16* __restrict__ qws, u16* __restrict__ kws, u16* __restrict__ vtws)
{
    __shared__ u16 As[128 * 32];
    __shared__ u16 Bs[128 * 32];
    const int t  = threadIdx.x;
    const int l  = t & 63;
    const int w  = t >> 6;
    const int cl = l & 15, gh = l >> 4;
    const int brow = blockIdx.x * 128;
    const int bcol = blockIdx.y * 128;
    const int wr = (w >> 1) * 64;
    const int wc = (w & 1) * 64;

    const int srow = w * 16 + (l >> 2);
    const int scol = (l & 3) * 8;
    const u16* gA = X + (size_t)(brow + srow) * 768 + scol;
    const u16* gB = W + (size_t)(bcol + srow) * 768 + scol;

    f32x4 acc[4][4] = {};

    for (int kt = 0; kt < 24; ++kt) {
        const int k0 = kt * 32;
        const s16x8 a0 = *(const s16x8*)(gA + k0);
        const s16x8 a1 = *(const s16x8*)(gA + k0 + 64 * 768);
        const s16x8 b0 = *(const s16x8*)(gB + k0);
        const s16x8 b1 = *(const s16x8*)(gB + k0 + 64 * 768);
        __syncthreads();
        *(s16x8*)(As + srow * 32 + scol)        = a0;
        *(s16x8*)(As + (srow + 64) * 32 + scol) = a1;
        *(s16x8*)(Bs + srow * 32 + scol)        = b0;
        *(s16x8*)(Bs + (srow + 64) * 32 + scol) = b1;
        __syncthreads();

        s16x8 af[4], bv[4];
        #pragma unroll
        for (int m = 0; m < 4; ++m)
            af[m] = *(const s16x8*)(As + (wr + m * 16 + cl) * 32 + gh * 8);
        #pragma unroll
        for (int n = 0; n < 4; ++n)
            bv[n] = *(const s16x8*)(Bs + (wc + n * 16 + cl) * 32 + gh * 8);
        #pragma unroll
        for (int m = 0; m < 4; ++m)
            #pragma unroll
            for (int n = 0; n < 4; ++n)
                acc[m][n] = MFMA16(af[m], bv[n], acc[m][n]);
    }

    const int seg   = (bcol + wc) >> 6;   // 0..35
    const int which = seg / 12;           // 0:q 1:k 2:v
    const int h     = seg % 12;
    // q pre-scale: 0.125 * log2(e) -> scores land in exp2 domain
    const float qscl = (which == 0) ? 0.1803368801111244f : 1.0f;

    #pragma unroll
    for (int m = 0; m < 4; ++m) {
        #pragma unroll
        for (int jj = 0; jj < 4; ++jj) {
            const int row = brow + wr + m * 16 + gh * 4 + jj;  // 0..4095
            const int b   = row >> 11;
            const int tok = row & 2047;
            if (which == 2) {
                u16* vtb = vtws + (size_t)(b * 12 + h) * 64 * 2048;
                #pragma unroll
                for (int n = 0; n < 4; ++n)
                    vtb[(size_t)(n * 16 + cl) * 2048 + tok] = f2bf(acc[m][n][jj]);
            } else {
                u16* outp = (which == 0) ? qws : kws;
                u16* orow = outp + ((size_t)(b * 12 + h) * 2048 + tok) * 64;
                const float* srow2 = SIN + tok * 64;
                const float* crow2 = COS + tok * 64;
                #pragma unroll
                for (int n = 0; n < 4; ++n) {
                    const int dh = n * 16 + cl;
                    const float v = acc[m][n][jj];
                    const float partner = (n < 2) ? -acc[m][n + 2][jj] : acc[m][n - 2][jj];
                    orow[dh] = f2bf((v * crow2[dh] + partner * srow2[dh]) * qscl);
                }
            }
        }
    }
}

// ---------------------------------------------------------------------------
// K2: flash attention, KV-split-4. grid 1536 x 256 threads.
// Block = 32 q-rows; 4 waves each process a disjoint 8-tile KV quarter.
// Round-8 inner loop (swapped QK^T, exp2 softmax w/ defer-max, bpermute P^T
// rearrange, K=32 PV) + K register double-buffer (next tile's K loads issued
// at tile top), native v_exp_f32, s_setprio around MFMA clusters.
// End: LDS combine of per-wave (m, l, O) partials; wave w merges n=w slice.
// ---------------------------------------------------------------------------
__global__ __launch_bounds__(256)
void k_attn(const u16* __restrict__ Qg, const u16* __restrict__ Kg,
            const u16* __restrict__ VTg, u16* __restrict__ Og)
{
    __shared__ f32x4 OL[4][64][8];    // [wave][lane][m*4+n] partial O^T, 32 KB
    __shared__ float2 ML[4][64][2];   // [wave][lane][m] = (m_run, l_run), 4 KB

    const int t  = threadIdx.x;
    const int l  = t & 63;
    const int w  = t >> 6;                      // 0..3 = KV quarter
    const int cl = l & 15, gh = l >> 4;

    // bijective swizzle: XCD (= i%8, assumed) owns 3 consecutive heads
    const int i  = blockIdx.x;                  // 0..1535
    const int bh = (i & 7) * 3 + ((i >> 3) % 3);
    const int qt = i / 24;                      // 0..63
    const int qb = qt * 32;                     // block's 32 q rows

    const u16* Q  = Qg  + (size_t)bh * 2048 * 64;
    const u16* K  = Kg  + (size_t)bh * 2048 * 64;
    const u16* VT = VTg + (size_t)bh * 64 * 2048;

    // Q B-fragments (same for all 4 waves): col q = qb+m*16+cl
    s16x8 qf[2][2];
    #pragma unroll
    for (int m = 0; m < 2; ++m)
        #pragma unroll
        for (int ks = 0; ks < 2; ++ks)
            qf[m][ks] = *(const s16x8*)(Q + (((qb + m * 16 + cl) << 6) + ks * 32 + gh * 8));

    f32x4 o[2][4] = {};            // O^T: lane col q=cl, row dh=n*16+gh*4+jj
    float mrun[2] = { -3e38f, -3e38f };
    float lrun[2] = { 0.f, 0.f };

    const int srcA = cl + (gh & 1) * 32;   // P^T rearrange source lanes
    const int srcB = srcA + 16;
    const bool loGH = (gh < 2);

    // per-lane int32 element-offset bases (advance by constants per tile)
    const int kbase0 = ((w * 8 * 64 + cl) << 6) + gh * 8;   // K: +nk*1024, +ks*32
    const int vbase0 = (cl << 11) + w * 8 * 64 + gh * 8;    // VT: +n*32768, +ks*32

    // K register double-buffer: prologue loads tile 0 into kfA
    s16x8 kfA[8], kfB[8];
    #pragma unroll
    for (int nk = 0; nk < 4; ++nk)
        #pragma unroll
        for (int ks = 0; ks < 2; ++ks)
            kfA[nk * 2 + ks] = *(const s16x8*)(K + (kbase0 + nk * 1024 + ks * 32));

// one KV tile; prefetches next tile's K into KF_NXT (wraps harmlessly at end)
#define ATTN_TILE(KT, KF_CUR, KF_NXT)                                          \
    {                                                                          \
        const int kb_n = kbase0 + (((KT) + 1) & 7) * 4096;                     \
        _Pragma("unroll")                                                      \
        for (int nk = 0; nk < 4; ++nk) {                                       \
            KF_NXT[nk * 2 + 0] = *(const s16x8*)(K + (kb_n + nk * 1024));      \
            KF_NXT[nk * 2 + 1] = *(const s16x8*)(K + (kb_n + nk * 1024 + 32)); \
        }                                                                      \
        const int vb = vbase0 + (KT) * 64;                                     \
        s16x8 vf[8];                                                           \
        _Pragma("unroll")                                                      \
        for (int n = 0; n < 4; ++n) {                                          \
            vf[n * 2 + 0] = *(const s16x8*)(VT + (vb + n * 32768));            \
            vf[n * 2 + 1] = *(const s16x8*)(VT + (vb + n * 32768 + 32));       \
        }                                                                      \
        f32x4 st[2][4] = {};                                                   \
        __builtin_amdgcn_s_setprio(1);                                         \
        _Pragma("unroll")                                                      \
        for (int nk = 0; nk < 4; ++nk)                                         \
            _Pragma("unroll")                                                  \
            for (int ks = 0; ks < 2; ++ks) {                                   \
                st[0][nk] = MFMA16(KF_CUR[nk * 2 + ks], qf[0][ks], st[0][nk]); \
                st[1][nk] = MFMA16(KF_CUR[nk * 2 + ks], qf[1][ks], st[1][nk]); \
            }                                                                  \
        __builtin_amdgcn_s_setprio(0);                                         \
        uint32_t d[2][4][2];                                                   \
        _Pragma("unroll")                                                      \
        for (int m = 0; m < 2; ++m) {                                          \
            float pm = st[m][0][0];                                            \
            _Pragma("unroll")                                                  \
            for (int nk = 0; nk < 4; ++nk)                                     \
                _Pragma("unroll")                                              \
                for (int jj = 0; jj < 4; ++jj)                                 \
                    pm = fmaxf(pm, st[m][nk][jj]);                             \
            pm = fmaxf(pm, __shfl_xor(pm, 16));                                \
            pm = fmaxf(pm, __shfl_xor(pm, 32));                                \
            if (!__all(pm - mrun[m] <= 8.f)) {                                 \
                const float mnew = fmaxf(mrun[m], pm);                         \
                const float al = fexp2(mrun[m] - mnew);                        \
                _Pragma("unroll")                                              \
                for (int n = 0; n < 4; ++n)                                    \
                    _Pragma("unroll")                                          \
                    for (int jj = 0; jj < 4; ++jj)                             \
                        o[m][n][jj] *= al;                                     \
                lrun[m] *= al;                                                 \
                mrun[m] = mnew;                                                \
            }                                                                  \
            float sum = 0.f;                                                   \
            _Pragma("unroll")                                                  \
            for (int nk = 0; nk < 4; ++nk) {                                   \
                const float p0 = fexp2(st[m][nk][0] - mrun[m]);                \
                const float p1 = fexp2(st[m][nk][1] - mrun[m]);                \
                const float p2 = fexp2(st[m][nk][2] - mrun[m]);                \
                const float p3 = fexp2(st[m][nk][3] - mrun[m]);                \
                sum += (p0 + p1) + (p2 + p3);                                  \
                d[m][nk][0] = pk2(p0, p1);                                     \
                d[m][nk][1] = pk2(p2, p3);                                     \
            }                                                                  \
            lrun[m] += sum;                                                    \
        }                                                                      \
        _Pragma("unroll")                                                      \
        for (int ks = 0; ks < 2; ++ks) {                                       \
            s16x8 pa[2];                                                       \
            _Pragma("unroll")                                                  \
            for (int m = 0; m < 2; ++m) {                                      \
                const uint32_t e0 = d[m][2 * ks][0], e1 = d[m][2 * ks][1];     \
                const uint32_t q0 = d[m][2 * ks + 1][0], q1 = d[m][2 * ks + 1][1]; \
                const uint32_t xE0 = (uint32_t)__shfl((int)e0, srcA);          \
                const uint32_t xE1 = (uint32_t)__shfl((int)e1, srcA);          \
                const uint32_t xE2 = (uint32_t)__shfl((int)e0, srcB);          \
                const uint32_t xE3 = (uint32_t)__shfl((int)e1, srcB);          \
                const uint32_t xO0 = (uint32_t)__shfl((int)q0, srcA);          \
                const uint32_t xO1 = (uint32_t)__shfl((int)q1, srcA);          \
                const uint32_t xO2 = (uint32_t)__shfl((int)q0, srcB);          \
                const uint32_t xO3 = (uint32_t)__shfl((int)q1, srcB);          \
                union { s16x8 v; uint32_t u[4]; } asm_;                        \
                asm_.u[0] = loGH ? xE0 : xO0;                                  \
                asm_.u[1] = loGH ? xE1 : xO1;                                  \
                asm_.u[2] = loGH ? xE2 : xO2;                                  \
                asm_.u[3] = loGH ? xE3 : xO3;                                  \
                pa[m] = asm_.v;                                                \
            }                                                                  \
            __builtin_amdgcn_s_setprio(1);                                     \
            _Pragma("unroll")                                                  \
            for (int n = 0; n < 4; ++n) {                                      \
                o[0][n] = MFMA16(vf[n * 2 + ks], pa[0], o[0][n]);              \
                o[1][n] = MFMA16(vf[n * 2 + ks], pa[1], o[1][n]);              \
            }                                                                  \
            __builtin_amdgcn_s_setprio(0);                                     \
        }                                                                      \
    }

    #pragma unroll
    for (int it = 0; it < 4; ++it) {
        ATTN_TILE(2 * it,     kfA, kfB)
        ATTN_TILE(2 * it + 1, kfB, kfA)
    }
#undef ATTN_TILE

    // ---- publish partials: reduce lrun across gh replicas, write LDS ----
    #pragma unroll
    for (int m = 0; m < 2; ++m) {
        float lr = lrun[m];
        lr += __shfl_xor(lr, 16);
        lr += __shfl_xor(lr, 32);
        ML[w][l][m] = make_float2(mrun[m], lr);
        #pragma unroll
        for (int n = 0; n < 4; ++n)
            OL[w][l][m * 4 + n] = o[m][n];
    }
    __syncthreads();

    // ---- combine: wave w merges the n=w slice of all 4 partials ----
    const int b = bh / 12, h = bh % 12;
    #pragma unroll
    for (int m = 0; m < 2; ++m) {
        float2 s[4];
        float mmax = -3e38f;
        #pragma unroll
        for (int w2 = 0; w2 < 4; ++w2) {
            s[w2] = ML[w2][l][m];
            mmax = fmaxf(mmax, s[w2].x);
        }
        f32x4 oacc = {};
        float lacc = 0.f;
        #pragma unroll
        for (int w2 = 0; w2 < 4; ++w2) {
            const float sc = fexp2(s[w2].x - mmax);
            oacc += OL[w2][l][m * 4 + w] * sc;
            lacc += s[w2].y * sc;
        }
        const float inv = 1.0f / lacc;
        const int tok = qb + m * 16 + cl;
        u16* orow = Og + ((size_t)(b * 2048 + tok)) * 768 + h * 64 + w * 16 + gh * 4;
        uint2 pkv;
        pkv.x = pk2(oacc[0] * inv, oacc[1] * inv);
        pkv.y = pk2(oacc[2] * inv, oacc[3] * inv);
        *(uint2*)orow = pkv;
    }
}

// ---------------------------------------------------------------------------
// K3: output projection + bias (fp32 out). grid (32, 6).
// ---------------------------------------------------------------------------
__global__ __launch_bounds__(256, 2)
void k_proj(const u16* __restrict__ A,      // [4096][768] bf16
            const u16* __restrict__ W,      // [768][768] bf16
            const float* __restrict__ BIAS, // [768] fp32
            float* __restrict__ OUT)        // [4096][768] fp32
{
    __shared__ u16 As[128 * 32];
    __shared__ u16 Bs[128 * 32];
    const int t  = threadIdx.x;
    const int l  = t & 63;
    const int w  = t >> 6;
    const int cl = l & 15, gh = l >> 4;
    const int brow = blockIdx.x * 128;
    const int bcol = blockIdx.y * 128;
    const int wr = (w >> 1) * 64;
    const int wc = (w & 1) * 64;

    const int srow = w * 16 + (l >> 2);
    const int scol = (l & 3) * 8;
    const u16* gA = A + (size_t)(brow + srow) * 768 + scol;
    const u16* gB = W + (size_t)(bcol + srow) * 768 + scol;

    f32x4 acc[4][4] = {};

    for (int kt = 0; kt < 24; ++kt) {
        const int k0 = kt * 32;
        const s16x8 a0 = *(const s16x8*)(gA + k0);
        const s16x8 a1 = *(const s16x8*)(gA + k0 + 64 * 768);
        const s16x8 b0 = *(const s16x8*)(gB + k0);
        const s16x8 b1 = *(const s16x8*)(gB + k0 + 64 * 768);
        __syncthreads();
        *(s16x8*)(As + srow * 32 + scol)        = a0;
        *(s16x8*)(As + (srow + 64) * 32 + scol) = a1;
        *(s16x8*)(Bs + srow * 32 + scol)        = b0;
        *(s16x8*)(Bs + (srow + 64) * 32 + scol) = b1;
        __syncthreads();

        s16x8 af[4], bv[4];
        #pragma unroll
        for (int m = 0; m < 4; ++m)
            af[m] = *(const s16x8*)(As + (wr + m * 16 + cl) * 32 + gh * 8);
        #pragma unroll
        for (int n = 0; n < 4; ++n)
            bv[n] = *(const s16x8*)(Bs + (wc + n * 16 + cl) * 32 + gh * 8);
        #pragma unroll
        for (int m = 0; m < 4; ++m)
            #pragma unroll
            for (int n = 0; n < 4; ++n)
                acc[m][n] = MFMA16(af[m], bv[n], acc[m][n]);
    }

    #pragma unroll
    for (int m = 0; m < 4; ++m) {
        #pragma unroll
        for (int jj = 0; jj < 4; ++jj) {
            const int row = brow + wr + m * 16 + gh * 4 + jj;
            #pragma unroll
            for (int n = 0; n < 4; ++n) {
                const int col = bcol + wc + n * 16 + cl;
                OUT[(size_t)row * 768 + col] = acc[m][n][jj] + BIAS[col];
            }
        }
    }
}

// ---------------------------------------------------------------------------
extern "C" void kernel_launch(void* const* d_in, const int* in_sizes, int n_in,
                              void* d_out, int out_size, void* d_ws, size_t ws_size,
                              hipStream_t stream)
{
    const float* x     = (const float*)d_in[0];
    const float* sinp  = (const float*)d_in[1];
    const float* cosp  = (const float*)d_in[2];
    const float* qkv_w = (const float*)d_in[3];
    const float* projw = (const float*)d_in[4];
    const float* projb = (const float*)d_in[5];
    float* out = (float*)d_out;

    const size_t N_X  = (size_t)4096 * 768;
    const size_t N_WQ = (size_t)2304 * 768;
    const size_t N_WP = (size_t)768 * 768;
    const size_t SEG  = (size_t)2 * 12 * 2048 * 64;

    u16* xbf   = (u16*)d_ws;
    u16* wqkv  = xbf + N_X;
    u16* wproj = wqkv + N_WQ;
    u16* qws   = wproj + N_WP;
    u16* kws   = qws + SEG;
    u16* vtws  = kws + SEG;   // transposed V [B,H,64,2048]
    u16* aws   = vtws + SEG;

    k_cvt<<<(int)(N_X  / 4 + 255) / 256, 256, 0, stream>>>(x,     xbf,   (int)(N_X  / 4));
    k_cvt<<<(int)(N_WQ / 4 + 255) / 256, 256, 0, stream>>>(qkv_w, wqkv,  (int)(N_WQ / 4));
    k_cvt<<<(int)(N_WP / 4 + 255) / 256, 256, 0, stream>>>(projw, wproj, (int)(N_WP / 4));

    k_qkv_rope<<<dim3(32, 18), 256, 0, stream>>>(xbf, wqkv, sinp, cosp, qws, kws, vtws);
    k_attn    <<<1536, 256, 0, stream>>>(qws, kws, vtws, aws);
    k_proj    <<<dim3(32, 6),  256, 0, stream>>>(aws, wproj, projb, out);
}